// Round 9
// baseline (549.850 us; speedup 1.0000x reference)
//
#include <hip/hip_runtime.h>
#include <hip/hip_bf16.h>

#define S_LEN 4096
#define DH 64
#define NBATCH 4

typedef __attribute__((ext_vector_type(8))) short bf16x8;   // 8 x bf16 (4 VGPRs)
typedef __attribute__((ext_vector_type(4))) short bf16x4;   // 4 x bf16
typedef __attribute__((ext_vector_type(4))) float f32x4;

static __device__ __forceinline__ short f2bf(float x) {
  __hip_bfloat16 h = __float2bfloat16(x);
  return *reinterpret_cast<short*>(&h);
}

// async global->LDS DMA, 16B/lane: LDS dest = wave-uniform base + lane*16,
// global src per-lane. Counts against vmcnt only.
static __device__ __forceinline__ void gl_lds16(const void* g, void* l) {
  __builtin_amdgcn_global_load_lds(
      (const __attribute__((address_space(1))) void*)g,
      (__attribute__((address_space(3))) void*)l, 16, 0, 0);
}

#define MFMA(a, b, c) __builtin_amdgcn_mfma_f32_16x16x32_bf16((a), (b), (c), 0, 0, 0)

// ---- q fp32 -> bf16 ----
__global__ __launch_bounds__(256) void cvt_q_kernel(const float* __restrict__ q,
                                                    short* __restrict__ qb) {
  int i = (blockIdx.x * 256 + threadIdx.x) * 4;
  f32x4 x = *(const f32x4*)(q + i);
  bf16x4 o;
#pragma unroll
  for (int j = 0; j < 4; ++j) o[j] = f2bf(x[j]);
  *(bf16x4*)(qb + i) = o;
}

// ---- k,v fp32 -> pre-fragmented bf16 MFMA operand layout (unchanged) ----
__global__ __launch_bounds__(256) void cvt_frag_kernel(const float* __restrict__ k,
                                                       const float* __restrict__ v,
                                                       short* __restrict__ kfrag,
                                                       short* __restrict__ vfrag) {
  __shared__ short kt[32][80];
  __shared__ short vt[32][80];
  const int t = threadIdx.x;
  const int b = blockIdx.x >> 7;
  const int i = blockIdx.x & 127;
  const size_t src0 = ((size_t)b * S_LEN + i * 32) * DH;
  {
    const int row = t >> 3, c0 = (t & 7) * 8;
    const f32x4 xk0 = *(const f32x4*)(k + src0 + row * DH + c0);
    const f32x4 xk1 = *(const f32x4*)(k + src0 + row * DH + c0 + 4);
    const f32x4 xv0 = *(const f32x4*)(v + src0 + row * DH + c0);
    const f32x4 xv1 = *(const f32x4*)(v + src0 + row * DH + c0 + 4);
#pragma unroll
    for (int j = 0; j < 4; ++j) {
      kt[row][c0 + j] = f2bf(xk0[j]);  kt[row][c0 + 4 + j] = f2bf(xk1[j]);
      vt[row][c0 + j] = f2bf(xv0[j]);  vt[row][c0 + 4 + j] = f2bf(xv1[j]);
    }
  }
  __syncthreads();
  const int c = t >> 6, l = t & 63;
  const size_t dst = (((size_t)(b * 128 + i) * 4 + c) * 64 + l) * 8;
  {
    const int kr = ((c >> 1) * 16) + (l & 15);
    const int d0 = ((c & 1) * 32) + (l >> 4) * 8;
    *(bf16x8*)(kfrag + dst) = *(const bf16x8*)&kt[kr][d0];
  }
  {
    bf16x8 f;
    const int col = c * 16 + (l & 15);
    const int r0 = (l >> 4) * 8;
#pragma unroll
    for (int j = 0; j < 8; ++j) f[j] = vt[r0 + j][col];
    *(bf16x8*)(vfrag + dst) = f;
  }
}

// ---- main flash-attention kernel: BYTE-IDENTICAL to R8 (control) ----
__global__ __launch_bounds__(512, 2) void fa_kernel(
    const short* __restrict__ qb, const short* __restrict__ kfrag,
    const short* __restrict__ vfrag, const float* __restrict__ mask,
    float* __restrict__ out) {
  __shared__ __align__(16) float mst[2][16384];      // 2 x 64KB mask stage
  __shared__ __align__(16) short lds_p[8][16][40];   // P round-trip

  const int tid = threadIdx.x;
  const int w = tid >> 6;          // 0..7
  const int wq = w >> 1;           // q-group 0..3 (16 rows each)
  const int wk = w & 1;            // key-split 0..1
  const int lane = tid & 63;
  const int quad = lane >> 4;
  const int n16 = lane & 15;
  const int loff = lane * 8;       // shorts

  const int vb = ((blockIdx.x & 7) << 5) | (blockIdx.x >> 3);
  const int b = vb >> 6;
  const int q0 = (vb & 63) << 6;   // 64 q-rows per block

  const int qr = q0 + wq * 16 + n16;
  const short* qrow = qb + (size_t)(b * S_LEN + qr) * DH;
  const bf16x8 aQ0 = *(const bf16x8*)(qrow + quad * 8);
  const bf16x8 aQ1 = *(const bf16x8*)(qrow + 32 + quad * 8);

  f32x4 O0 = {0.f, 0.f, 0.f, 0.f}, O1 = O0, O2 = O0, O3 = O0;
  float lacc = 0.f;

  const short* kfb = kfrag + (size_t)(b * 128 + wk) * 2048;
  const short* vfb = vfrag + (size_t)(b * 128 + wk) * 2048;
  bf16x8 kA0, kA1, kA2, kA3, kB0, kB1, kB2, kB3;
  bf16x8 vA0, vA1, vA2, vA3, vB0, vB1, vB2, vB3;

  const float* mbase =
      mask + ((size_t)b * S_LEN + q0 + w * 8) * S_LEN;   // row w*8, col 0
  const int mr = wq * 16 + n16;
  const int mx = n16 & 7;
  int rs0[4], rs1[4];
#pragma unroll
  for (int ssl = 0; ssl < 4; ++ssl) {
    rs0[ssl] = mr * 256 + (((ssl * 16) + wk * 8 + quad) ^ mx) * 4;
    rs1[ssl] = mr * 256 + (((ssl * 16) + wk * 8 + 4 + quad) ^ mx) * 4;
  }

#define STAGE(BUF, SS)                                                     \
  {                                                                        \
    const int c0_ = (SS) * 256;                                            \
    _Pragma("unroll") for (int j = 0; j < 8; ++j) {                        \
      gl_lds16(mbase + (size_t)j * S_LEN + c0_ + ((lane ^ j) << 2),        \
               (char*)&mst[BUF][0] + (w * 8 + j) * 1024);                  \
    }                                                                      \
  }

#define LOAD_BK(B0, B1, B2, B3, SS)                       \
  {                                                       \
    const short* kf_ = kfb + (size_t)(SS) * 4096 + loff;  \
    B0 = *(const bf16x8*)(kf_);                           \
    B1 = *(const bf16x8*)(kf_ + 512);                     \
    B2 = *(const bf16x8*)(kf_ + 1024);                    \
    B3 = *(const bf16x8*)(kf_ + 1536);                    \
  }

#define LOAD_BV(V0, V1, V2, V3, SS)                       \
  {                                                       \
    const short* vf_ = vfb + (size_t)(SS) * 4096 + loff;  \
    V0 = *(const bf16x8*)(vf_);                           \
    V1 = *(const bf16x8*)(vf_ + 512);                     \
    V2 = *(const bf16x8*)(vf_ + 1024);                    \
    V3 = *(const bf16x8*)(vf_ + 1536);                    \
  }

#define SUB(K0, K1, K2, K3, V0, V1, V2, V3, MB, SSL, GS)                   \
  {                                                                        \
    const f32x4 z = {0.f, 0.f, 0.f, 0.f};                                  \
    f32x4 s0 = MFMA(K0, aQ0, z); s0 = MFMA(K1, aQ1, s0);                   \
    f32x4 s1 = MFMA(K2, aQ0, z); s1 = MFMA(K3, aQ1, s1);                   \
    LOAD_BK(K0, K1, K2, K3, ((GS) + 2) & 63); /* refill, dist 2 */         \
    const f32x4 M0 = *(const f32x4*)((MB) + rs0[SSL]);                     \
    const f32x4 M1 = *(const f32x4*)((MB) + rs1[SSL]);                     \
    float p0_[4], p1_[4];                                                  \
    _Pragma("unroll") for (int r = 0; r < 4; ++r) {                        \
      p0_[r] = __expf(s0[r] * 0.125f * M0[r]);                             \
      p1_[r] = __expf(s1[r] * 0.125f * M1[r]);                             \
      lacc += p0_[r] + p1_[r];                                             \
    }                                                                      \
    bf16x4 w0_, w1_;                                                       \
    _Pragma("unroll") for (int r = 0; r < 4; ++r) {                        \
      w0_[r] = f2bf(p0_[r]); w1_[r] = f2bf(p1_[r]);                        \
    }                                                                      \
    *(bf16x4*)&lds_p[w][n16][quad * 4] = w0_;                              \
    *(bf16x4*)&lds_p[w][n16][16 + quad * 4] = w1_;                         \
    const bf16x8 aP = *(const bf16x8*)&lds_p[w][n16][quad * 8];            \
    O0 = MFMA(aP, V0, O0); O1 = MFMA(aP, V1, O1);                          \
    O2 = MFMA(aP, V2, O2); O3 = MFMA(aP, V3, O3);                          \
    LOAD_BV(V0, V1, V2, V3, ((GS) + 2) & 63); /* refill, dist 2 */         \
  }

  STAGE(0, 0);
  LOAD_BK(kA0, kA1, kA2, kA3, 0);
  LOAD_BV(vA0, vA1, vA2, vA3, 0);
  LOAD_BK(kB0, kB1, kB2, kB3, 1);
  LOAD_BV(vB0, vB1, vB2, vB3, 1);
  asm volatile("s_waitcnt vmcnt(16)\n\ts_barrier" ::: "memory");

  int buf = 0;
#pragma unroll 1
  for (int s = 0; s < 16; ++s) {
    STAGE(buf ^ 1, (s + 1) & 15);
    const float* mb = &mst[buf][0];
    const int gs = s * 4;
    SUB(kA0, kA1, kA2, kA3, vA0, vA1, vA2, vA3, mb, 0, gs);
    SUB(kB0, kB1, kB2, kB3, vB0, vB1, vB2, vB3, mb, 1, gs + 1);
    SUB(kA0, kA1, kA2, kA3, vA0, vA1, vA2, vA3, mb, 2, gs + 2);
    SUB(kB0, kB1, kB2, kB3, vB0, vB1, vB2, vB3, mb, 3, gs + 3);
    asm volatile("s_waitcnt vmcnt(16)\n\ts_barrier" ::: "memory");
    buf ^= 1;
  }
#undef STAGE
#undef LOAD_BK
#undef LOAD_BV
#undef SUB

  asm volatile("s_waitcnt vmcnt(0)\n\ts_barrier" ::: "memory");

  float* ldsO = &mst[0][0];   // [8][16][64] = 32 KB
  float* ldsl = &mst[1][0];   // [8][16]

  lacc += __shfl_xor(lacc, 16);
  lacc += __shfl_xor(lacc, 32);

#pragma unroll
  for (int r = 0; r < 4; ++r) {
    const int row = quad * 4 + r;
    float* od = ldsO + (w * 16 + row) * 64;
    od[n16]      = O0[r];
    od[16 + n16] = O1[r];
    od[32 + n16] = O2[r];
    od[48 + n16] = O3[r];
  }
  if (lane < 16) ldsl[w * 16 + lane] = lacc;
  __syncthreads();

  const int g = tid >> 7;
  const int rr = (tid >> 3) & 15;
  const int c8 = (tid & 7) << 3;
  const int wa = g * 2, wb = g * 2 + 1;
  const float inv = 1.0f / (ldsl[wa * 16 + rr] + ldsl[wb * 16 + rr]);
  const float* oap = ldsO + (wa * 16 + rr) * 64 + c8;
  const float* obp = ldsO + (wb * 16 + rr) * 64 + c8;
  float* op = out + (size_t)(b * S_LEN + q0 + g * 16 + rr) * DH + c8;
  f32x4 acc0, acc1;
#pragma unroll
  for (int j = 0; j < 4; ++j) {
    acc0[j] = (oap[j]     + obp[j])     * inv;
    acc1[j] = (oap[4 + j] + obp[4 + j]) * inv;
  }
  *(f32x4*)(op) = acc0;
  *(f32x4*)(op + 4) = acc1;
}

// ================= R9 MEASUREMENT PROBES (read-only, run after fa) =========
// probe_seq: best-case sequential read of the full mask, TWICE (536 MB,
// defeats L3). grid 1024x256; 4 independent f32x4 loads in flight/thread at
// grid stride (perfectly coalesced). Measures the machine's peak read BW.
__global__ __launch_bounds__(256) void probe_seq(const float* __restrict__ m,
                                                 float* __restrict__ sink) {
  const size_t N4 = (size_t)NBATCH * S_LEN * S_LEN / 4;   // 16,777,216 f32x4
  const size_t S = (size_t)gridDim.x * 256;               // 262,144 threads
  const size_t base = (size_t)blockIdx.x * 256 + threadIdx.x;
  float s0 = 0.f, s1 = 0.f, s2 = 0.f, s3 = 0.f;
#pragma unroll 1
  for (int pass = 0; pass < 2; ++pass) {
#pragma unroll 1
    for (size_t i = base; i + 3 * S < N4; i += 4 * S) {
      const f32x4 a = *(const f32x4*)(m + (i)         * 4);
      const f32x4 c = *(const f32x4*)(m + (i + S)     * 4);
      const f32x4 d = *(const f32x4*)(m + (i + 2 * S) * 4);
      const f32x4 e = *(const f32x4*)(m + (i + 3 * S) * 4);
      s0 += a[0] + a[1] + a[2] + a[3];
      s1 += c[0] + c[1] + c[2] + c[3];
      s2 += d[0] + d[1] + d[2] + d[3];
      s3 += e[0] + e[1] + e[2] + e[3];
    }
  }
  if (s0 + s1 + s2 + s3 == -1.0f) sink[0] = s0;   // impossible: keeps loads live
}

// probe_pat: the R1 fa mask access pattern (16 rows x 64B per instr, 128-col
// steps, same XCD remap), TWICE, unroll-4 (8 loads in flight) — the pattern's
// intrinsic BW, divorced from fa's compute/LDS/MFMA.
__global__ __launch_bounds__(256) void probe_pat(const float* __restrict__ mask,
                                                 float* __restrict__ sink) {
  const int tid = threadIdx.x;
  const int w = tid >> 6;
  const int lane = tid & 63;
  const int quad = lane >> 4;
  const int n16 = lane & 15;
  const int vb = ((blockIdx.x & 7) << 7) | (blockIdx.x >> 3);
  const int b = vb >> 8;
  const int q0 = (vb & 255) << 4;
  const float* mrow = mask + ((size_t)b * S_LEN + q0 + n16) * S_LEN + quad * 4;
  float s0 = 0.f, s1 = 0.f;
#pragma unroll 1
  for (int pass = 0; pass < 2; ++pass) {
#pragma unroll 4
    for (int s = 0; s < 32; ++s) {
      const int lk = s * 128 + w * 32;
      const f32x4 a = *(const f32x4*)(mrow + lk);
      const f32x4 c = *(const f32x4*)(mrow + lk + 16);
      s0 += a[0] + a[1] + a[2] + a[3];
      s1 += c[0] + c[1] + c[2] + c[3];
    }
  }
  if (s0 + s1 == -1.0f) sink[1] = s0;   // impossible: keeps loads live
}

extern "C" void kernel_launch(void* const* d_in, const int* in_sizes, int n_in,
                              void* d_out, int out_size, void* d_ws, size_t ws_size,
                              hipStream_t stream) {
  const float* q = (const float*)d_in[0];
  const float* k = (const float*)d_in[1];
  const float* v = (const float*)d_in[2];
  const float* mask = (const float*)d_in[3];
  float* out = (float*)d_out;

  short* qb = (short*)d_ws;                                  // 2 MB
  short* kfrag = qb + (size_t)NBATCH * S_LEN * DH;           // 2 MB
  short* vfrag = kfrag + (size_t)NBATCH * S_LEN * DH;        // 2 MB

  cvt_q_kernel<<<(NBATCH * S_LEN * DH) / 1024, 256, 0, stream>>>(q, qb);
  cvt_frag_kernel<<<NBATCH * 128, 256, 0, stream>>>(k, v, kfrag, vfrag);
  fa_kernel<<<NBATCH * 64, 512, 0, stream>>>(qb, kfrag, vfrag, mask, out);

  // ---- measurement probes (qb is dead after fa; sink write never fires) ----
  float* sink = (float*)d_ws;
  probe_pat<<<NBATCH * 256, 256, 0, stream>>>(mask, sink);
  probe_seq<<<1024, 256, 0, stream>>>(mask, sink);
}